// Round 25
// baseline (204.680 us; speedup 1.0000x reference)
//
#include <hip/hip_runtime.h>
#include <cstdint>
#include <cstddef>

#define F_IN 165
#define KP   192      // K padded to multiple of 32
#define HC1  256      // heads*out_ch of layer 1
#define NEG_SLOPE 0.2f

typedef __attribute__((ext_vector_type(8))) short short8;
typedef __attribute__((ext_vector_type(8))) unsigned short ushort8;
typedef __attribute__((ext_vector_type(4))) float f32x4;
typedef __attribute__((ext_vector_type(2))) float f32x2;

static __device__ __forceinline__ float lrelu(float z) {
    return z > 0.f ? z : NEG_SLOPE * z;
}
static __device__ __forceinline__ unsigned short f2b(float v) {
    union { float f; unsigned u; } x; x.f = v;
    unsigned r = (x.u + 0x7FFFu + ((x.u >> 16) & 1u)) >> 16;   // RNE
    return (unsigned short)r;
}
static __device__ __forceinline__ float b2f(unsigned short u) {
    return __uint_as_float(((unsigned)u) << 16);
}
static __device__ __forceinline__ unsigned char f2f8(float v) {
    int pk_ = __builtin_amdgcn_cvt_pk_fp8_f32(v, 0.f, 0, false);
    return (unsigned char)(pk_ & 0xff);
}
// XOR swizzle within a row (row = 384 B): byte' = byte ^ ((r&7)<<4); bijective in-row.
static __device__ __forceinline__ int swzb(int r, int kbyte) {
    return r * (KP * 2) + (kbyte ^ ((r & 7) << 4));
}

// ---- prep: W1 -> w1t swizzled | folded att weights watt[16][192] | edge count ----
__global__ void k_prepw_count(const float* __restrict__ W1,
                              const float* __restrict__ as1, const float* __restrict__ ad1,
                              unsigned short* __restrict__ w1t,
                              unsigned short* __restrict__ watt,
                              const int* __restrict__ dst, int* __restrict__ deg,
                              unsigned short* __restrict__ pos, int E)
{
    const int A = HC1 * 48;
    const int B_ = 16 * 48;
    int i = blockIdx.x * 256 + threadIdx.x;
    if (i < A) {
        int nc = i / 48, q = i - nc * 48;
        int k = q * 4;
        ushort4 o;
        o.x = f2b((k + 0 < F_IN) ? W1[(size_t)(k + 0) * HC1 + nc] : 0.f);
        o.y = f2b((k + 1 < F_IN) ? W1[(size_t)(k + 1) * HC1 + nc] : 0.f);
        o.z = f2b((k + 2 < F_IN) ? W1[(size_t)(k + 2) * HC1 + nc] : 0.f);
        o.w = f2b((k + 3 < F_IN) ? W1[(size_t)(k + 3) * HC1 + nc] : 0.f);
        int byte = (8 * q) ^ ((nc & 7) << 4);
        *reinterpret_cast<ushort4*>((char*)w1t + (size_t)nc * (KP * 2) + byte) = o;
    } else if (i < A + B_) {
        int i2 = i - A;
        int j = i2 / 48, q = i2 - j * 48;
        int k = q * 4;
        unsigned short ov[4] = {0, 0, 0, 0};
        if (j < 8) {
            const float* av = ((j < 4) ? as1 : ad1) + (j & 3) * 64;
            const int cbase = (j & 3) * 64;
            #pragma unroll
            for (int kk = 0; kk < 4; ++kk) {
                int kq = k + kk;
                float s = 0.f;
                if (kq < F_IN) {
                    const float* wrow = W1 + (size_t)kq * HC1 + cbase;
                    for (int c = 0; c < 64; ++c) s += wrow[c] * av[c];
                }
                ov[kk] = f2b(s);
            }
        }
        ushort4 o; o.x = ov[0]; o.y = ov[1]; o.z = ov[2]; o.w = ov[3];
        *reinterpret_cast<ushort4*>(watt + (size_t)j * KP + k) = o;
    } else {
        int base = (i - A - B_) * 4;
        if (base >= E) return;
        if (base + 4 <= E) {
            int4 d = *reinterpret_cast<const int4*>(dst + base);
            pos[base + 0] = (unsigned short)atomicAdd(&deg[d.x], 1);
            pos[base + 1] = (unsigned short)atomicAdd(&deg[d.y], 1);
            pos[base + 2] = (unsigned short)atomicAdd(&deg[d.z], 1);
            pos[base + 3] = (unsigned short)atomicAdd(&deg[d.w], 1);
        } else {
            for (int j2 = base; j2 < E; ++j2)
                pos[j2] = (unsigned short)atomicAdd(&deg[dst[j2]], 1);
        }
    }
}

// -------- GEMM1 (bf16 MFMA): fused X staging; C stored FP8; att via extra MFMA -------
__global__ __launch_bounds__(256) void k_gemm1b(const float* __restrict__ x,
        const unsigned short* __restrict__ w1t, const unsigned short* __restrict__ watt,
        unsigned char* __restrict__ h1f8,
        float* __restrict__ asrc1, float* __restrict__ adst1, int M)
{
    __shared__ unsigned short xs[64 * KP];
    __shared__ unsigned short wt[64 * KP];
    const int t = threadIdx.x;
    const int row0 = blockIdx.x * 64;
    const int vr = min(64, M - row0);        // valid rows in this tile
    const int totF = vr * F_IN;

    // zero pad columns 165..191 (all 64 rows)
    for (int i = t; i < 64 * (KP - F_IN); i += 256) {
        int r = i / (KP - F_IN), k = F_IN + (i - r * (KP - F_IN));
        *(unsigned short*)((char*)xs + swzb(r, 2 * k)) = 0;
    }
    // zero out-of-range rows (k<165)
    if (vr < 64) {
        for (int i = t; i < (64 - vr) * F_IN; i += 256) {
            int r = vr + i / F_IN, k = i - (i / F_IN) * F_IN;
            *(unsigned short*)((char*)xs + swzb(r, 2 * k)) = 0;
        }
    }
    // stage X: linear float4 over the contiguous vr x 165 fp32 tile (base 16B-aligned)
    {
        const float* gx = x + (size_t)row0 * F_IN;
        const int nCh = totF >> 2;
        for (int c = t; c < nCh; c += 256) {
            const float4 v = *reinterpret_cast<const float4*>(gx + c * 4);
            float vv[4] = { v.x, v.y, v.z, v.w };
            int L = c * 4;
            int r = L / F_IN;
            int k = L - r * F_IN;
            #pragma unroll
            for (int j = 0; j < 4; ++j) {
                *(unsigned short*)((char*)xs + swzb(r, 2 * k)) = f2b(vv[j]);
                if (++k == F_IN) { k = 0; ++r; }
            }
        }
        for (int e = (totF & ~3) + t; e < totF; e += 256) {
            int r = e / F_IN, k = e - r * F_IN;
            *(unsigned short*)((char*)xs + swzb(r, 2 * k)) = f2b(gx[e]);
        }
    }

    const int l = t & 63, wid = t >> 6;
    const int wr = wid >> 1, wc = wid & 1;
    for (int cb = 0; cb < 4; ++cb) {
        if (cb) __syncthreads();              // prev cb's wt reads done
        const char* gw = (const char*)w1t + (size_t)(cb * 64) * (KP * 2);
        #pragma unroll
        for (int i = 0; i < 6; ++i) {
            int o_ = i * 4096 + t * 16;
            *reinterpret_cast<ushort8*>((char*)wt + o_) =
                *reinterpret_cast<const ushort8*>(gw + o_);
        }
        __syncthreads();                      // xs + wt staged
        f32x4 acc[2][2] = {};
        #pragma unroll
        for (int ks = 0; ks < KP / 32; ++ks) {
            const int kb = ks * 32 + (l >> 4) * 8;
            short8 a[2], b[2];
            #pragma unroll
            for (int f = 0; f < 2; ++f) {
                int ar = wr * 32 + f * 16 + (l & 15);
                a[f] = *reinterpret_cast<const short8*>((const char*)xs + swzb(ar, 2 * kb));
                int bc = wc * 32 + f * 16 + (l & 15);
                b[f] = *reinterpret_cast<const short8*>((const char*)wt + swzb(bc, 2 * kb));
            }
            #pragma unroll
            for (int fi = 0; fi < 2; ++fi)
                #pragma unroll
                for (int fj = 0; fj < 2; ++fj)
                    acc[fi][fj] = __builtin_amdgcn_mfma_f32_16x16x32_bf16(a[fi], b[fj], acc[fi][fj], 0, 0, 0);
        }
        // C write (fp8 e4m3, HW-encoded)
        #pragma unroll
        for (int fi = 0; fi < 2; ++fi) {
            #pragma unroll
            for (int q = 0; q < 4; ++q) {
                int r = row0 + wr * 32 + fi * 16 + (l >> 4) * 4 + q;
                if (r < M) {
                    #pragma unroll
                    for (int fj = 0; fj < 2; ++fj) {
                        int cidx = cb * 64 + wc * 32 + fj * 16 + (l & 15);
                        h1f8[(size_t)r * HC1 + cidx] = f2f8(acc[fi][fj][q]);
                    }
                }
            }
        }
    }
    // ---- att-scalar tile: 16 cols (4 asrc | 4 adst | 8 pad), B from global watt ----
    {
        const int fi = wc;                    // wave (wr,wc) computes fragment fi=wc
        f32x4 acca = {};
        #pragma unroll
        for (int ks = 0; ks < KP / 32; ++ks) {
            const int kb = ks * 32 + (l >> 4) * 8;
            int ar = wr * 32 + fi * 16 + (l & 15);
            short8 a = *reinterpret_cast<const short8*>((const char*)xs + swzb(ar, 2 * kb));
            short8 b = *reinterpret_cast<const short8*>(watt + (size_t)(l & 15) * KP + kb);
            acca = __builtin_amdgcn_mfma_f32_16x16x32_bf16(a, b, acca, 0, 0, 0);
        }
        const int j = l & 15;
        #pragma unroll
        for (int q = 0; q < 4; ++q) {
            int r = row0 + wr * 32 + fi * 16 + (l >> 4) * 4 + q;
            if (r < M) {
                if (j < 4)       asrc1[r * 4 + j] = acca[q];
                else if (j < 8)  adst1[r * 4 + (j - 4)] = acca[q];
            }
        }
    }
}

// -------------------- CSR scans --------------------
__global__ __launch_bounds__(256) void k_scanA(const int* __restrict__ deg,
                                               int* __restrict__ off,
                                               int* __restrict__ bsums, int n)
{
    __shared__ int s[256];
    const int b = blockIdx.x, t = threadIdx.x;
    const int base = b * 1024 + t * 4;
    int v[4]; int sum = 0;
    #pragma unroll
    for (int j = 0; j < 4; ++j) { v[j] = (base + j < n) ? deg[base + j] + 1 : 0; sum += v[j]; }
    s[t] = sum;
    __syncthreads();
    for (int d = 1; d < 256; d <<= 1) {
        int xv = (t >= d) ? s[t - d] : 0;
        __syncthreads();
        s[t] += xv;
        __syncthreads();
    }
    int run = s[t] - sum;
    #pragma unroll
    for (int j = 0; j < 4; ++j) { run += v[j]; if (base + j < n) off[base + j + 1] = run; }
    if (t == 255) bsums[b] = s[255];
    if (b == 0 && t == 0) off[0] = 0;
}
// folded scanB+scanC + self-loop scatter
__global__ __launch_bounds__(256) void k_scanC(int* __restrict__ off,
                                               const int* __restrict__ bsums,
                                               int* __restrict__ srcs, int n)
{
    __shared__ int red[256];
    const int t = threadIdx.x;
    const int ch = (blockIdx.x * 256) >> 10;     // constant within block
    int part = 0;
    for (int j = t; j < ch; j += 256) part += bsums[j];
    red[t] = part;
    __syncthreads();
    for (int d = 128; d > 0; d >>= 1) {
        if (t < d) red[t] += red[t + d];
        __syncthreads();
    }
    const int base = red[0];
    int i = blockIdx.x * 256 + t;
    if (i < n) {
        int v = off[i + 1] + base;
        off[i + 1] = v;
        srcs[v - 1] = i;                          // self loop at end of segment
    }
}
// scatter edges only, NO atomics, 4 edges/thread vectorized
__global__ void k_scatter(const int* __restrict__ src, const int* __restrict__ dst,
                          const unsigned short* __restrict__ pos,
                          const int* __restrict__ off, int* __restrict__ srcs, int E)
{
    int base = (blockIdx.x * blockDim.x + threadIdx.x) * 4;
    if (base + 4 <= E) {
        int4 s4 = *reinterpret_cast<const int4*>(src + base);
        int4 d4 = *reinterpret_cast<const int4*>(dst + base);
        ushort4 p4 = *reinterpret_cast<const ushort4*>(pos + base);
        srcs[off[d4.x] + p4.x] = s4.x;
        srcs[off[d4.y] + p4.y] = s4.y;
        srcs[off[d4.z] + p4.z] = s4.z;
        srcs[off[d4.w] + p4.w] = s4.w;
    } else {
        for (int j = base; j < E; ++j) srcs[off[dst[j]] + pos[j]] = src[j];
    }
}

// ---- attention weights: SINGLE pass, no-max exp (validated R10), bf16 w + f32 1/sum
__global__ void k_alpha(const float* __restrict__ asrc1, const float* __restrict__ adst1,
                        const int* __restrict__ off, const int* __restrict__ srcs,
                        unsigned short* __restrict__ alphab, float* __restrict__ inv4,
                        int N)
{
    int n = blockIdx.x * blockDim.x + threadIdx.x;
    if (n >= N) return;
    const float4 ad = reinterpret_cast<const float4*>(adst1)[n];
    const int p0 = off[n], p1 = off[n + 1];
    float s0 = 0.f, s1 = 0.f, s2 = 0.f, s3 = 0.f;
    for (int p = p0; p < p1; ++p) {
        const float4 as = reinterpret_cast<const float4*>(asrc1)[srcs[p]];
        float z0 = __expf(lrelu(as.x + ad.x));
        float z1 = __expf(lrelu(as.y + ad.y));
        float z2 = __expf(lrelu(as.z + ad.z));
        float z3 = __expf(lrelu(as.w + ad.w));
        ushort4 zb;
        zb.x = f2b(z0); zb.y = f2b(z1); zb.z = f2b(z2); zb.w = f2b(z3);
        reinterpret_cast<ushort4*>(alphab)[p] = zb;
        s0 += b2f(zb.x); s1 += b2f(zb.y); s2 += b2f(zb.z); s3 += b2f(zb.w);
    }
    float4 iv; iv.x = 1.f / s0; iv.y = 1.f / s1; iv.z = 1.f / s2; iv.w = 1.f / s3;
    reinterpret_cast<float4*>(inv4)[n] = iv;
}

// ---------- layer-1 aggregation: fp8 h1 gather, 16-edge register unroll --------------
// wave per node; lane owns 4 contiguous channels (head = lane>>4)
__global__ __launch_bounds__(256) void k_agg1b(const unsigned char* __restrict__ h1f8,
        const unsigned short* __restrict__ alphab, const float* __restrict__ inv4,
        const int* __restrict__ off, const int* __restrict__ srcs,
        const float* __restrict__ b1, const float* __restrict__ W2,
        const float* __restrict__ as2, const float* __restrict__ ad2,
        float* __restrict__ pk, float* __restrict__ adst2, int N)
{
    const int lane = threadIdx.x & 63;
    const int n = blockIdx.x * 4 + (threadIdx.x >> 6);
    if (n >= N) return;
    const int head = lane >> 4;
    const int p0 = off[n], p1 = off[n + 1];
    float a0 = 0.f, a1 = 0.f, a2 = 0.f, a3 = 0.f;
    int p = p0;
    for (; p + 16 <= p1; p += 16) {
        int s[16]; float al[16]; unsigned hv[16];
        #pragma unroll
        for (int j = 0; j < 16; ++j) s[j] = srcs[p + j];
        #pragma unroll
        for (int j = 0; j < 16; ++j) al[j] = b2f(alphab[(size_t)(p + j) * 4 + head]);
        #pragma unroll
        for (int j = 0; j < 16; ++j)
            hv[j] = *reinterpret_cast<const unsigned*>(h1f8 + (size_t)s[j] * HC1 + lane * 4);
        #pragma unroll
        for (int j = 0; j < 16; ++j) {
            f32x2 lo = __builtin_amdgcn_cvt_pk_f32_fp8(hv[j], false);
            f32x2 hi = __builtin_amdgcn_cvt_pk_f32_fp8(hv[j], true);
            a0 += al[j] * lo[0]; a1 += al[j] * lo[1];
            a2 += al[j] * hi[0]; a3 += al[j] * hi[1];
        }
    }
    for (; p + 8 <= p1; p += 8) {
        int s[8]; float al[8]; unsigned hv[8];
        #pragma unroll
        for (int j = 0; j < 8; ++j) s[j] = srcs[p + j];
        #pragma unroll
        for (int j = 0; j < 8; ++j) al[j] = b2f(alphab[(size_t)(p + j) * 4 + head]);
        #pragma unroll
        for (int j = 0; j < 8; ++j)
            hv[j] = *reinterpret_cast<const unsigned*>(h1f8 + (size_t)s[j] * HC1 + lane * 4);
        #pragma unroll
        for (int j = 0; j < 8; ++j) {
            f32x2 lo = __builtin_amdgcn_cvt_pk_f32_fp8(hv[j], false);
            f32x2 hi = __builtin_amdgcn_cvt_pk_f32_fp8(hv[j], true);
            a0 += al[j] * lo[0]; a1 += al[j] * lo[1];
            a2 += al[j] * hi[0]; a3 += al[j] * hi[1];
        }
    }
    for (; p + 4 <= p1; p += 4) {
        int s[4]; float al[4]; unsigned hv[4];
        #pragma unroll
        for (int j = 0; j < 4; ++j) s[j] = srcs[p + j];
        #pragma unroll
        for (int j = 0; j < 4; ++j) al[j] = b2f(alphab[(size_t)(p + j) * 4 + head]);
        #pragma unroll
        for (int j = 0; j < 4; ++j)
            hv[j] = *reinterpret_cast<const unsigned*>(h1f8 + (size_t)s[j] * HC1 + lane * 4);
        #pragma unroll
        for (int j = 0; j < 4; ++j) {
            f32x2 lo = __builtin_amdgcn_cvt_pk_f32_fp8(hv[j], false);
            f32x2 hi = __builtin_amdgcn_cvt_pk_f32_fp8(hv[j], true);
            a0 += al[j] * lo[0]; a1 += al[j] * lo[1];
            a2 += al[j] * hi[0]; a3 += al[j] * hi[1];
        }
    }
    for (; p < p1; ++p) {
        const int s = srcs[p];
        const float al = b2f(alphab[(size_t)p * 4 + head]);
        const unsigned hv = *reinterpret_cast<const unsigned*>(h1f8 + (size_t)s * HC1 + lane * 4);
        f32x2 lo = __builtin_amdgcn_cvt_pk_f32_fp8(hv, false);
        f32x2 hi = __builtin_amdgcn_cvt_pk_f32_fp8(hv, true);
        a0 += al * lo[0]; a1 += al * lo[1];
        a2 += al * hi[0]; a3 += al * hi[1];
    }
    const float inv = inv4[n * 4 + head];
    const float4 bb = *reinterpret_cast<const float4*>(b1 + lane * 4);
    a0 = fmaxf(a0 * inv + bb.x, 0.f); a1 = fmaxf(a1 * inv + bb.y, 0.f);
    a2 = fmaxf(a2 * inv + bb.z, 0.f); a3 = fmaxf(a3 * inv + bb.w, 0.f);
    // layer-2 projection: out-row (256) @ W2 (256x2)
    const float4 wA = *reinterpret_cast<const float4*>(W2 + lane * 8);
    const float4 wB = *reinterpret_cast<const float4*>(W2 + lane * 8 + 4);
    float q0 = a0 * wA.x + a1 * wA.z + a2 * wB.x + a3 * wB.z;
    float q1 = a0 * wA.y + a1 * wA.w + a2 * wB.y + a3 * wB.w;
    #pragma unroll
    for (int d = 1; d < 64; d <<= 1) {
        q0 += __shfl_xor(q0, d, 64);
        q1 += __shfl_xor(q1, d, 64);
    }
    if (lane == 0) {
        float sA = q0 * as2[0] + q1 * as2[1];
        reinterpret_cast<float4*>(pk)[n] = make_float4(q0, q1, sA, 0.f);
        adst2[n] = q0 * ad2[0] + q1 * ad2[1];
    }
}

// ---------- layer-2 aggregation + log_softmax: packed gather, no-max exp, 4-unroll ----
__global__ void k_l2(const float* __restrict__ pk, const float* __restrict__ adst2,
                     const int* __restrict__ off, const int* __restrict__ srcs,
                     const float* __restrict__ b2, float* __restrict__ out, int N)
{
    int n = blockIdx.x * blockDim.x + threadIdx.x;
    if (n >= N) return;
    const float adn = adst2[n];
    const float4* pk4 = reinterpret_cast<const float4*>(pk);
    float ssum = 0.f, a0 = 0.f, a1 = 0.f;
    int p = off[n];
    const int p1 = off[n + 1];
    for (; p + 4 <= p1; p += 4) {
        int s[4]; float4 v[4];
        #pragma unroll
        for (int j = 0; j < 4; ++j) s[j] = srcs[p + j];
        #pragma unroll
        for (int j = 0; j < 4; ++j) v[j] = pk4[s[j]];
        #pragma unroll
        for (int j = 0; j < 4; ++j) {
            const float w = __expf(lrelu(v[j].z + adn));
            ssum += w;
            a0 += w * v[j].x;
            a1 += w * v[j].y;
        }
    }
    for (; p < p1; ++p) {
        const float4 v = pk4[srcs[p]];
        const float w = __expf(lrelu(v.z + adn));
        ssum += w;
        a0 += w * v.x;
        a1 += w * v.y;
    }
    const float invs = 1.f / ssum;
    float o0 = a0 * invs + b2[0];
    float o1 = a1 * invs + b2[1];
    float mm = fmaxf(o0, o1);
    float lse = mm + __logf(__expf(o0 - mm) + __expf(o1 - mm));
    out[n * 2 + 0] = o0 - lse;
    out[n * 2 + 1] = o1 - lse;
}

extern "C" void kernel_launch(void* const* d_in, const int* in_sizes, int n_in,
                              void* d_out, int out_size, void* d_ws, size_t ws_size,
                              hipStream_t stream)
{
    const float* x   = (const float*)d_in[0];
    const int*   ei  = (const int*)d_in[1];
    const float* W1  = (const float*)d_in[2];
    const float* as1 = (const float*)d_in[3];
    const float* ad1 = (const float*)d_in[4];
    const float* b1  = (const float*)d_in[5];
    const float* W2  = (const float*)d_in[6];
    const float* as2 = (const float*)d_in[7];
    const float* ad2 = (const float*)d_in[8];
    const float* b2  = (const float*)d_in[9];
    float* out = (float*)d_out;

    const int N = in_sizes[0] / F_IN;
    const int E = in_sizes[1] / 2;
    const int Nr = (N + 63) & ~63;
    const int* esrc = ei;
    const int* edst = ei + E;

    char* ws = (char*)d_ws;
    size_t o = 0;
    auto alloc = [&](size_t bytes) -> void* {
        o = (o + 255) & ~(size_t)255;
        void* p = ws + o;
        o += bytes;
        return p;
    };
    unsigned short* w1t  = (unsigned short*)alloc((size_t)HC1 * KP * 2);
    unsigned short* watt = (unsigned short*)alloc((size_t)16 * KP * 2);
    unsigned char*  h1f8 = (unsigned char*)alloc((size_t)N * HC1);
    float* asrc1 = (float*)alloc((size_t)N * 4 * 4);
    float* adst1 = (float*)alloc((size_t)N * 4 * 4);
    unsigned short* alphab = (unsigned short*)alloc((size_t)(E + N) * 4 * 2);
    float* inv4  = (float*)alloc((size_t)N * 4 * 4);
    float* pk    = (float*)alloc((size_t)N * 4 * 4);
    float* adst2 = (float*)alloc((size_t)N * 4);
    int*   deg   = (int*)alloc((size_t)N * 4);
    int*   off   = (int*)alloc((size_t)(N + 1) * 4);
    unsigned short* pos = (unsigned short*)alloc((size_t)E * 2);
    int*   srcs  = (int*)alloc((size_t)(E + N) * 4);
    int*   bsums = (int*)alloc(512);

    // deg must be zero before the fused count
    hipMemsetAsync(deg, 0, (size_t)N * 4, stream);
    // W1 prep + folded att weights + edge count (fused)
    int pcItems = HC1 * 48 + 16 * 48 + (E + 3) / 4;
    k_prepw_count<<<(pcItems + 255) / 256, 256, 0, stream>>>(W1, as1, ad1, w1t, watt,
                                                             edst, deg, pos, E);
    // GEMM with in-kernel X staging; fp8 C; att scalars via extra MFMA tile
    k_gemm1b<<<Nr / 64, 256, 0, stream>>>(x, w1t, watt, h1f8, asrc1, adst1, N);

    // CSR: scanA -> scanC(folded B + self-loops) -> scatter(edges)
    int B = (N + 1023) / 1024;
    k_scanA<<<B, 256, 0, stream>>>(deg, off, bsums, N);
    k_scanC<<<(N + 255) / 256, 256, 0, stream>>>(off, bsums, srcs, N);
    k_scatter<<<(E / 4 + 255) / 256, 256, 0, stream>>>(esrc, edst, pos, off, srcs, E);

    // attention weights, aggregation, layer 2
    k_alpha<<<(N + 255) / 256, 256, 0, stream>>>(asrc1, adst1, off, srcs, alphab, inv4, N);
    k_agg1b<<<(N + 3) / 4, 256, 0, stream>>>(h1f8, alphab, inv4, off, srcs, b1, W2,
                                             as2, ad2, pk, adst2, N);
    k_l2<<<(N + 255) / 256, 256, 0, stream>>>(pk, adst2, off, srcs, b2, out, N);
}

// Round 26
// 187.239 us; speedup vs baseline: 1.0931x; 1.0931x over previous
//
#include <hip/hip_runtime.h>
#include <cstdint>
#include <cstddef>

#define F_IN 165
#define KP   192      // K padded to multiple of 32
#define HC1  256      // heads*out_ch of layer 1
#define NEG_SLOPE 0.2f

typedef __attribute__((ext_vector_type(8))) short short8;
typedef __attribute__((ext_vector_type(8))) unsigned short ushort8;
typedef __attribute__((ext_vector_type(4))) float f32x4;
typedef __attribute__((ext_vector_type(2))) float f32x2;

static __device__ __forceinline__ float lrelu(float z) {
    return z > 0.f ? z : NEG_SLOPE * z;
}
static __device__ __forceinline__ unsigned short f2b(float v) {
    union { float f; unsigned u; } x; x.f = v;
    unsigned r = (x.u + 0x7FFFu + ((x.u >> 16) & 1u)) >> 16;   // RNE
    return (unsigned short)r;
}
static __device__ __forceinline__ float b2f(unsigned short u) {
    return __uint_as_float(((unsigned)u) << 16);
}
static __device__ __forceinline__ unsigned char f2f8(float v) {
    int pk_ = __builtin_amdgcn_cvt_pk_fp8_f32(v, 0.f, 0, false);
    return (unsigned char)(pk_ & 0xff);
}
// XOR swizzle within a row (row = 384 B): byte' = byte ^ ((r&7)<<4); bijective in-row.
static __device__ __forceinline__ int swzb(int r, int kbyte) {
    return r * (KP * 2) + (kbyte ^ ((r & 7) << 4));
}

// ---- prep: W1 -> w1t swizzled | folded att weights watt[16][192] | edge count ----
__global__ void k_prepw_count(const float* __restrict__ W1,
                              const float* __restrict__ as1, const float* __restrict__ ad1,
                              unsigned short* __restrict__ w1t,
                              unsigned short* __restrict__ watt,
                              const int* __restrict__ dst, int* __restrict__ deg,
                              unsigned short* __restrict__ pos, int E)
{
    const int A = HC1 * 48;
    const int B_ = 16 * 48;
    int i = blockIdx.x * 256 + threadIdx.x;
    if (i < A) {
        int nc = i / 48, q = i - nc * 48;
        int k = q * 4;
        ushort4 o;
        o.x = f2b((k + 0 < F_IN) ? W1[(size_t)(k + 0) * HC1 + nc] : 0.f);
        o.y = f2b((k + 1 < F_IN) ? W1[(size_t)(k + 1) * HC1 + nc] : 0.f);
        o.z = f2b((k + 2 < F_IN) ? W1[(size_t)(k + 2) * HC1 + nc] : 0.f);
        o.w = f2b((k + 3 < F_IN) ? W1[(size_t)(k + 3) * HC1 + nc] : 0.f);
        int byte = (8 * q) ^ ((nc & 7) << 4);
        *reinterpret_cast<ushort4*>((char*)w1t + (size_t)nc * (KP * 2) + byte) = o;
    } else if (i < A + B_) {
        int i2 = i - A;
        int j = i2 / 48, q = i2 - j * 48;
        int k = q * 4;
        unsigned short ov[4] = {0, 0, 0, 0};
        if (j < 8) {
            const float* av = ((j < 4) ? as1 : ad1) + (j & 3) * 64;
            const int cbase = (j & 3) * 64;
            #pragma unroll
            for (int kk = 0; kk < 4; ++kk) {
                int kq = k + kk;
                float s = 0.f;
                if (kq < F_IN) {
                    const float* wrow = W1 + (size_t)kq * HC1 + cbase;
                    for (int c = 0; c < 64; ++c) s += wrow[c] * av[c];
                }
                ov[kk] = f2b(s);
            }
        }
        ushort4 o; o.x = ov[0]; o.y = ov[1]; o.z = ov[2]; o.w = ov[3];
        *reinterpret_cast<ushort4*>(watt + (size_t)j * KP + k) = o;
    } else {
        int base = (i - A - B_) * 4;
        if (base >= E) return;
        if (base + 4 <= E) {
            int4 d = *reinterpret_cast<const int4*>(dst + base);
            pos[base + 0] = (unsigned short)atomicAdd(&deg[d.x], 1);
            pos[base + 1] = (unsigned short)atomicAdd(&deg[d.y], 1);
            pos[base + 2] = (unsigned short)atomicAdd(&deg[d.z], 1);
            pos[base + 3] = (unsigned short)atomicAdd(&deg[d.w], 1);
        } else {
            for (int j2 = base; j2 < E; ++j2)
                pos[j2] = (unsigned short)atomicAdd(&deg[dst[j2]], 1);
        }
    }
}

// -------- GEMM1 (bf16 MFMA): fused X staging; C stored FP8; att via extra MFMA -------
__global__ __launch_bounds__(256) void k_gemm1b(const float* __restrict__ x,
        const unsigned short* __restrict__ w1t, const unsigned short* __restrict__ watt,
        unsigned char* __restrict__ h1f8,
        float* __restrict__ asrc1, float* __restrict__ adst1, int M)
{
    __shared__ unsigned short xs[64 * KP];
    __shared__ unsigned short wt[64 * KP];
    const int t = threadIdx.x;
    const int row0 = blockIdx.x * 64;
    const int vr = min(64, M - row0);        // valid rows in this tile
    const int totF = vr * F_IN;

    // zero pad columns 165..191 (all 64 rows)
    for (int i = t; i < 64 * (KP - F_IN); i += 256) {
        int r = i / (KP - F_IN), k = F_IN + (i - r * (KP - F_IN));
        *(unsigned short*)((char*)xs + swzb(r, 2 * k)) = 0;
    }
    // zero out-of-range rows (k<165)
    if (vr < 64) {
        for (int i = t; i < (64 - vr) * F_IN; i += 256) {
            int r = vr + i / F_IN, k = i - (i / F_IN) * F_IN;
            *(unsigned short*)((char*)xs + swzb(r, 2 * k)) = 0;
        }
    }
    // stage X: linear float4 over the contiguous vr x 165 fp32 tile (base 16B-aligned)
    {
        const float* gx = x + (size_t)row0 * F_IN;
        const int nCh = totF >> 2;
        for (int c = t; c < nCh; c += 256) {
            const float4 v = *reinterpret_cast<const float4*>(gx + c * 4);
            float vv[4] = { v.x, v.y, v.z, v.w };
            int L = c * 4;
            int r = L / F_IN;
            int k = L - r * F_IN;
            #pragma unroll
            for (int j = 0; j < 4; ++j) {
                *(unsigned short*)((char*)xs + swzb(r, 2 * k)) = f2b(vv[j]);
                if (++k == F_IN) { k = 0; ++r; }
            }
        }
        for (int e = (totF & ~3) + t; e < totF; e += 256) {
            int r = e / F_IN, k = e - r * F_IN;
            *(unsigned short*)((char*)xs + swzb(r, 2 * k)) = f2b(gx[e]);
        }
    }

    const int l = t & 63, wid = t >> 6;
    const int wr = wid >> 1, wc = wid & 1;
    for (int cb = 0; cb < 4; ++cb) {
        if (cb) __syncthreads();              // prev cb's wt reads done
        const char* gw = (const char*)w1t + (size_t)(cb * 64) * (KP * 2);
        #pragma unroll
        for (int i = 0; i < 6; ++i) {
            int o_ = i * 4096 + t * 16;
            *reinterpret_cast<ushort8*>((char*)wt + o_) =
                *reinterpret_cast<const ushort8*>(gw + o_);
        }
        __syncthreads();                      // xs + wt staged
        f32x4 acc[2][2] = {};
        #pragma unroll
        for (int ks = 0; ks < KP / 32; ++ks) {
            const int kb = ks * 32 + (l >> 4) * 8;
            short8 a[2], b[2];
            #pragma unroll
            for (int f = 0; f < 2; ++f) {
                int ar = wr * 32 + f * 16 + (l & 15);
                a[f] = *reinterpret_cast<const short8*>((const char*)xs + swzb(ar, 2 * kb));
                int bc = wc * 32 + f * 16 + (l & 15);
                b[f] = *reinterpret_cast<const short8*>((const char*)wt + swzb(bc, 2 * kb));
            }
            #pragma unroll
            for (int fi = 0; fi < 2; ++fi)
                #pragma unroll
                for (int fj = 0; fj < 2; ++fj)
                    acc[fi][fj] = __builtin_amdgcn_mfma_f32_16x16x32_bf16(a[fi], b[fj], acc[fi][fj], 0, 0, 0);
        }
        // C write (fp8 e4m3, HW-encoded)
        #pragma unroll
        for (int fi = 0; fi < 2; ++fi) {
            #pragma unroll
            for (int q = 0; q < 4; ++q) {
                int r = row0 + wr * 32 + fi * 16 + (l >> 4) * 4 + q;
                if (r < M) {
                    #pragma unroll
                    for (int fj = 0; fj < 2; ++fj) {
                        int cidx = cb * 64 + wc * 32 + fj * 16 + (l & 15);
                        h1f8[(size_t)r * HC1 + cidx] = f2f8(acc[fi][fj][q]);
                    }
                }
            }
        }
    }
    // ---- att-scalar tile: 16 cols (4 asrc | 4 adst | 8 pad), B from global watt ----
    {
        const int fi = wc;                    // wave (wr,wc) computes fragment fi=wc
        f32x4 acca = {};
        #pragma unroll
        for (int ks = 0; ks < KP / 32; ++ks) {
            const int kb = ks * 32 + (l >> 4) * 8;
            int ar = wr * 32 + fi * 16 + (l & 15);
            short8 a = *reinterpret_cast<const short8*>((const char*)xs + swzb(ar, 2 * kb));
            short8 b = *reinterpret_cast<const short8*>(watt + (size_t)(l & 15) * KP + kb);
            acca = __builtin_amdgcn_mfma_f32_16x16x32_bf16(a, b, acca, 0, 0, 0);
        }
        const int j = l & 15;
        #pragma unroll
        for (int q = 0; q < 4; ++q) {
            int r = row0 + wr * 32 + fi * 16 + (l >> 4) * 4 + q;
            if (r < M) {
                if (j < 4)       asrc1[r * 4 + j] = acca[q];
                else if (j < 8)  adst1[r * 4 + (j - 4)] = acca[q];
            }
        }
    }
}

// -------------------- CSR scans --------------------
__global__ __launch_bounds__(256) void k_scanA(const int* __restrict__ deg,
                                               int* __restrict__ off,
                                               int* __restrict__ bsums, int n)
{
    __shared__ int s[256];
    const int b = blockIdx.x, t = threadIdx.x;
    const int base = b * 1024 + t * 4;
    int v[4]; int sum = 0;
    #pragma unroll
    for (int j = 0; j < 4; ++j) { v[j] = (base + j < n) ? deg[base + j] + 1 : 0; sum += v[j]; }
    s[t] = sum;
    __syncthreads();
    for (int d = 1; d < 256; d <<= 1) {
        int xv = (t >= d) ? s[t - d] : 0;
        __syncthreads();
        s[t] += xv;
        __syncthreads();
    }
    int run = s[t] - sum;
    #pragma unroll
    for (int j = 0; j < 4; ++j) { run += v[j]; if (base + j < n) off[base + j + 1] = run; }
    if (t == 255) bsums[b] = s[255];
    if (b == 0 && t == 0) off[0] = 0;
}
// folded scanB+scanC + self-loop scatter
__global__ __launch_bounds__(256) void k_scanC(int* __restrict__ off,
                                               const int* __restrict__ bsums,
                                               int* __restrict__ srcs, int n)
{
    __shared__ int red[256];
    const int t = threadIdx.x;
    const int ch = (blockIdx.x * 256) >> 10;     // constant within block
    int part = 0;
    for (int j = t; j < ch; j += 256) part += bsums[j];
    red[t] = part;
    __syncthreads();
    for (int d = 128; d > 0; d >>= 1) {
        if (t < d) red[t] += red[t + d];
        __syncthreads();
    }
    const int base = red[0];
    int i = blockIdx.x * 256 + t;
    if (i < n) {
        int v = off[i + 1] + base;
        off[i + 1] = v;
        srcs[v - 1] = i;                          // self loop at end of segment
    }
}
// scatter edges only, NO atomics, 4 edges/thread vectorized
__global__ void k_scatter(const int* __restrict__ src, const int* __restrict__ dst,
                          const unsigned short* __restrict__ pos,
                          const int* __restrict__ off, int* __restrict__ srcs, int E)
{
    int base = (blockIdx.x * blockDim.x + threadIdx.x) * 4;
    if (base + 4 <= E) {
        int4 s4 = *reinterpret_cast<const int4*>(src + base);
        int4 d4 = *reinterpret_cast<const int4*>(dst + base);
        ushort4 p4 = *reinterpret_cast<const ushort4*>(pos + base);
        srcs[off[d4.x] + p4.x] = s4.x;
        srcs[off[d4.y] + p4.y] = s4.y;
        srcs[off[d4.z] + p4.z] = s4.z;
        srcs[off[d4.w] + p4.w] = s4.w;
    } else {
        for (int j = base; j < E; ++j) srcs[off[dst[j]] + pos[j]] = src[j];
    }
}

// ---- attention weights: SINGLE pass, no-max exp (validated R10), bf16 w + f32 1/sum
__global__ void k_alpha(const float* __restrict__ asrc1, const float* __restrict__ adst1,
                        const int* __restrict__ off, const int* __restrict__ srcs,
                        unsigned short* __restrict__ alphab, float* __restrict__ inv4,
                        int N)
{
    int n = blockIdx.x * blockDim.x + threadIdx.x;
    if (n >= N) return;
    const float4 ad = reinterpret_cast<const float4*>(adst1)[n];
    const int p0 = off[n], p1 = off[n + 1];
    float s0 = 0.f, s1 = 0.f, s2 = 0.f, s3 = 0.f;
    for (int p = p0; p < p1; ++p) {
        const float4 as = reinterpret_cast<const float4*>(asrc1)[srcs[p]];
        float z0 = __expf(lrelu(as.x + ad.x));
        float z1 = __expf(lrelu(as.y + ad.y));
        float z2 = __expf(lrelu(as.z + ad.z));
        float z3 = __expf(lrelu(as.w + ad.w));
        ushort4 zb;
        zb.x = f2b(z0); zb.y = f2b(z1); zb.z = f2b(z2); zb.w = f2b(z3);
        reinterpret_cast<ushort4*>(alphab)[p] = zb;
        s0 += b2f(zb.x); s1 += b2f(zb.y); s2 += b2f(zb.z); s3 += b2f(zb.w);
    }
    float4 iv; iv.x = 1.f / s0; iv.y = 1.f / s1; iv.z = 1.f / s2; iv.w = 1.f / s3;
    reinterpret_cast<float4*>(inv4)[n] = iv;
}

// ---------- layer-1 aggregation: fp8 h1 gather (4B/lane), streamed bf16 alpha --------
// wave per node; lane owns 4 contiguous channels (head = lane>>4); 8-edge unroll
__global__ __launch_bounds__(256) void k_agg1b(const unsigned char* __restrict__ h1f8,
        const unsigned short* __restrict__ alphab, const float* __restrict__ inv4,
        const int* __restrict__ off, const int* __restrict__ srcs,
        const float* __restrict__ b1, const float* __restrict__ W2,
        const float* __restrict__ as2, const float* __restrict__ ad2,
        float* __restrict__ pk, float* __restrict__ adst2, int N)
{
    const int lane = threadIdx.x & 63;
    const int n = blockIdx.x * 4 + (threadIdx.x >> 6);
    if (n >= N) return;
    const int head = lane >> 4;
    const int p0 = off[n], p1 = off[n + 1];
    float a0 = 0.f, a1 = 0.f, a2 = 0.f, a3 = 0.f;
    int p = p0;
    for (; p + 8 <= p1; p += 8) {
        int s[8]; float al[8]; unsigned hv[8];
        #pragma unroll
        for (int j = 0; j < 8; ++j) s[j] = srcs[p + j];
        #pragma unroll
        for (int j = 0; j < 8; ++j) al[j] = b2f(alphab[(size_t)(p + j) * 4 + head]);
        #pragma unroll
        for (int j = 0; j < 8; ++j)
            hv[j] = *reinterpret_cast<const unsigned*>(h1f8 + (size_t)s[j] * HC1 + lane * 4);
        #pragma unroll
        for (int j = 0; j < 8; ++j) {
            f32x2 lo = __builtin_amdgcn_cvt_pk_f32_fp8(hv[j], false);
            f32x2 hi = __builtin_amdgcn_cvt_pk_f32_fp8(hv[j], true);
            a0 += al[j] * lo[0]; a1 += al[j] * lo[1];
            a2 += al[j] * hi[0]; a3 += al[j] * hi[1];
        }
    }
    for (; p + 4 <= p1; p += 4) {
        int s[4]; float al[4]; unsigned hv[4];
        #pragma unroll
        for (int j = 0; j < 4; ++j) s[j] = srcs[p + j];
        #pragma unroll
        for (int j = 0; j < 4; ++j) al[j] = b2f(alphab[(size_t)(p + j) * 4 + head]);
        #pragma unroll
        for (int j = 0; j < 4; ++j)
            hv[j] = *reinterpret_cast<const unsigned*>(h1f8 + (size_t)s[j] * HC1 + lane * 4);
        #pragma unroll
        for (int j = 0; j < 4; ++j) {
            f32x2 lo = __builtin_amdgcn_cvt_pk_f32_fp8(hv[j], false);
            f32x2 hi = __builtin_amdgcn_cvt_pk_f32_fp8(hv[j], true);
            a0 += al[j] * lo[0]; a1 += al[j] * lo[1];
            a2 += al[j] * hi[0]; a3 += al[j] * hi[1];
        }
    }
    for (; p < p1; ++p) {
        const int s = srcs[p];
        const float al = b2f(alphab[(size_t)p * 4 + head]);
        const unsigned hv = *reinterpret_cast<const unsigned*>(h1f8 + (size_t)s * HC1 + lane * 4);
        f32x2 lo = __builtin_amdgcn_cvt_pk_f32_fp8(hv, false);
        f32x2 hi = __builtin_amdgcn_cvt_pk_f32_fp8(hv, true);
        a0 += al * lo[0]; a1 += al * lo[1];
        a2 += al * hi[0]; a3 += al * hi[1];
    }
    const float inv = inv4[n * 4 + head];
    const float4 bb = *reinterpret_cast<const float4*>(b1 + lane * 4);
    a0 = fmaxf(a0 * inv + bb.x, 0.f); a1 = fmaxf(a1 * inv + bb.y, 0.f);
    a2 = fmaxf(a2 * inv + bb.z, 0.f); a3 = fmaxf(a3 * inv + bb.w, 0.f);
    // layer-2 projection: out-row (256) @ W2 (256x2)
    const float4 wA = *reinterpret_cast<const float4*>(W2 + lane * 8);
    const float4 wB = *reinterpret_cast<const float4*>(W2 + lane * 8 + 4);
    float q0 = a0 * wA.x + a1 * wA.z + a2 * wB.x + a3 * wB.z;
    float q1 = a0 * wA.y + a1 * wA.w + a2 * wB.y + a3 * wB.w;
    #pragma unroll
    for (int d = 1; d < 64; d <<= 1) {
        q0 += __shfl_xor(q0, d, 64);
        q1 += __shfl_xor(q1, d, 64);
    }
    if (lane == 0) {
        float sA = q0 * as2[0] + q1 * as2[1];
        reinterpret_cast<float4*>(pk)[n] = make_float4(q0, q1, sA, 0.f);
        adst2[n] = q0 * ad2[0] + q1 * ad2[1];
    }
}

// ---------- layer-2 aggregation + log_softmax: packed gather, no-max exp, 4-unroll ----
__global__ void k_l2(const float* __restrict__ pk, const float* __restrict__ adst2,
                     const int* __restrict__ off, const int* __restrict__ srcs,
                     const float* __restrict__ b2, float* __restrict__ out, int N)
{
    int n = blockIdx.x * blockDim.x + threadIdx.x;
    if (n >= N) return;
    const float adn = adst2[n];
    const float4* pk4 = reinterpret_cast<const float4*>(pk);
    float ssum = 0.f, a0 = 0.f, a1 = 0.f;
    int p = off[n];
    const int p1 = off[n + 1];
    for (; p + 4 <= p1; p += 4) {
        int s[4]; float4 v[4];
        #pragma unroll
        for (int j = 0; j < 4; ++j) s[j] = srcs[p + j];
        #pragma unroll
        for (int j = 0; j < 4; ++j) v[j] = pk4[s[j]];
        #pragma unroll
        for (int j = 0; j < 4; ++j) {
            const float w = __expf(lrelu(v[j].z + adn));
            ssum += w;
            a0 += w * v[j].x;
            a1 += w * v[j].y;
        }
    }
    for (; p < p1; ++p) {
        const float4 v = pk4[srcs[p]];
        const float w = __expf(lrelu(v.z + adn));
        ssum += w;
        a0 += w * v.x;
        a1 += w * v.y;
    }
    const float invs = 1.f / ssum;
    float o0 = a0 * invs + b2[0];
    float o1 = a1 * invs + b2[1];
    float mm = fmaxf(o0, o1);
    float lse = mm + __logf(__expf(o0 - mm) + __expf(o1 - mm));
    out[n * 2 + 0] = o0 - lse;
    out[n * 2 + 1] = o1 - lse;
}

extern "C" void kernel_launch(void* const* d_in, const int* in_sizes, int n_in,
                              void* d_out, int out_size, void* d_ws, size_t ws_size,
                              hipStream_t stream)
{
    const float* x   = (const float*)d_in[0];
    const int*   ei  = (const int*)d_in[1];
    const float* W1  = (const float*)d_in[2];
    const float* as1 = (const float*)d_in[3];
    const float* ad1 = (const float*)d_in[4];
    const float* b1  = (const float*)d_in[5];
    const float* W2  = (const float*)d_in[6];
    const float* as2 = (const float*)d_in[7];
    const float* ad2 = (const float*)d_in[8];
    const float* b2  = (const float*)d_in[9];
    float* out = (float*)d_out;

    const int N = in_sizes[0] / F_IN;
    const int E = in_sizes[1] / 2;
    const int Nr = (N + 63) & ~63;
    const int* esrc = ei;
    const int* edst = ei + E;

    char* ws = (char*)d_ws;
    size_t o = 0;
    auto alloc = [&](size_t bytes) -> void* {
        o = (o + 255) & ~(size_t)255;
        void* p = ws + o;
        o += bytes;
        return p;
    };
    unsigned short* w1t  = (unsigned short*)alloc((size_t)HC1 * KP * 2);
    unsigned short* watt = (unsigned short*)alloc((size_t)16 * KP * 2);
    unsigned char*  h1f8 = (unsigned char*)alloc((size_t)N * HC1);
    float* asrc1 = (float*)alloc((size_t)N * 4 * 4);
    float* adst1 = (float*)alloc((size_t)N * 4 * 4);
    unsigned short* alphab = (unsigned short*)alloc((size_t)(E + N) * 4 * 2);
    float* inv4  = (float*)alloc((size_t)N * 4 * 4);
    float* pk    = (float*)alloc((size_t)N * 4 * 4);
    float* adst2 = (float*)alloc((size_t)N * 4);
    int*   deg   = (int*)alloc((size_t)N * 4);
    int*   off   = (int*)alloc((size_t)(N + 1) * 4);
    unsigned short* pos = (unsigned short*)alloc((size_t)E * 2);
    int*   srcs  = (int*)alloc((size_t)(E + N) * 4);
    int*   bsums = (int*)alloc(512);

    // deg must be zero before the fused count
    hipMemsetAsync(deg, 0, (size_t)N * 4, stream);
    // W1 prep + folded att weights + edge count (fused)
    int pcItems = HC1 * 48 + 16 * 48 + (E + 3) / 4;
    k_prepw_count<<<(pcItems + 255) / 256, 256, 0, stream>>>(W1, as1, ad1, w1t, watt,
                                                             edst, deg, pos, E);
    // GEMM with in-kernel X staging; fp8 C; att scalars via extra MFMA tile
    k_gemm1b<<<Nr / 64, 256, 0, stream>>>(x, w1t, watt, h1f8, asrc1, adst1, N);

    // CSR: scanA -> scanC(folded B + self-loops) -> scatter(edges)
    int B = (N + 1023) / 1024;
    k_scanA<<<B, 256, 0, stream>>>(deg, off, bsums, N);
    k_scanC<<<(N + 255) / 256, 256, 0, stream>>>(off, bsums, srcs, N);
    k_scatter<<<(E / 4 + 255) / 256, 256, 0, stream>>>(esrc, edst, pos, off, srcs, E);

    // attention weights, aggregation, layer 2
    k_alpha<<<(N + 255) / 256, 256, 0, stream>>>(asrc1, adst1, off, srcs, alphab, inv4, N);
    k_agg1b<<<(N + 3) / 4, 256, 0, stream>>>(h1f8, alphab, inv4, off, srcs, b1, W2,
                                             as2, ad2, pk, adst2, N);
    k_l2<<<(N + 255) / 256, 256, 0, stream>>>(pk, adst2, off, srcs, b2, out, N);
}